// Round 10
// baseline (663.556 us; speedup 1.0000x reference)
//
#include <hip/hip_runtime.h>
#include <hip/hip_fp16.h>
#include <cstdint>
#include <cstddef>

#define NNODES 50000
#define NEDGES 800000
#define E2 (NEDGES + NNODES)
#define HC 256

typedef __attribute__((ext_vector_type(8))) short short8v;  // 8 bf16 = 4 VGPR (MFMA A/B frag)
typedef __attribute__((ext_vector_type(4))) float f32x4;    // MFMA C/D frag
typedef const __attribute__((address_space(1))) void* gas_t;
typedef __attribute__((address_space(3))) void* las_t;

// ---------------- CSR build ----------------

__global__ void zero_int(int* __restrict__ p, int n) {
    int i = blockIdx.x * 256 + threadIdx.x;
    if (i < n) p[i] = 0;
}

__global__ void count_deg(const int* __restrict__ ei, int* __restrict__ deg) {
    int i = blockIdx.x * 256 + threadIdx.x;
    if (i >= E2) return;
    int d = (i < NEDGES) ? ei[NEDGES + i] : (i - NEDGES);
    atomicAdd(&deg[d], 1);
}

__global__ void scan1(const int* __restrict__ deg, int* __restrict__ rp, int* __restrict__ bs) {
    __shared__ int s[256];
    int t = threadIdx.x, i = blockIdx.x * 256 + t;
    int v = (i < NNODES) ? deg[i] : 0;
    s[t] = v;
    __syncthreads();
    for (int o = 1; o < 256; o <<= 1) {
        int add = (t >= o) ? s[t - o] : 0;
        __syncthreads();
        s[t] += add;
        __syncthreads();
    }
    if (i < NNODES) rp[i] = s[t] - v;
    if (t == 255) bs[blockIdx.x] = s[255];
}

__global__ void scan2(int* __restrict__ bs, int nb) {
    __shared__ int s[256];
    int t = threadIdx.x;
    int v = (t < nb) ? bs[t] : 0;
    s[t] = v;
    __syncthreads();
    for (int o = 1; o < 256; o <<= 1) {
        int add = (t >= o) ? s[t - o] : 0;
        __syncthreads();
        s[t] += add;
        __syncthreads();
    }
    bs[t] = s[t] - v;
}

__global__ void scan3(int* __restrict__ rp, const int* __restrict__ bs, int* __restrict__ cnt) {
    int i = blockIdx.x * 256 + threadIdx.x;
    if (i < NNODES) {
        int v = rp[i] + bs[blockIdx.x];
        rp[i] = v;
        cnt[i] = v;
    }
    if (i == 0) rp[NNODES] = E2;
}

__global__ void fill_csr(const int* __restrict__ ei, int* __restrict__ cnt, int* __restrict__ csr) {
    int i = blockIdx.x * 256 + threadIdx.x;
    if (i >= E2) return;
    int s, d;
    if (i < NEDGES) { s = ei[i]; d = ei[NEDGES + i]; }
    else            { s = d = i - NEDGES; }
    int pos = atomicAdd(&cnt[d], 1);
    csr[pos] = s;
}

// ---------------- fp32 -> split bf16 (hi + residual-lo), RNE ----------------

__device__ __forceinline__ unsigned short f2bf(float f) {
    uint32_t u = __float_as_uint(f);
    uint32_t r = (u + 0x7FFFu + ((u >> 16) & 1u)) >> 16;
    return (unsigned short)r;
}
__device__ __forceinline__ float bf2f(unsigned short h) {
    return __uint_as_float(((uint32_t)h) << 16);
}

__global__ void split_bf16(const float* __restrict__ in, unsigned short* __restrict__ hi,
                           unsigned short* __restrict__ lo, int n4) {
    int i = blockIdx.x * 256 + threadIdx.x;
    if (i >= n4) return;
    float4 v = ((const float4*)in)[i];
    unsigned short h0 = f2bf(v.x), h1 = f2bf(v.y), h2 = f2bf(v.z), h3 = f2bf(v.w);
    unsigned short l0 = f2bf(v.x - bf2f(h0));
    unsigned short l1 = f2bf(v.y - bf2f(h1));
    unsigned short l2 = f2bf(v.z - bf2f(h2));
    unsigned short l3 = f2bf(v.w - bf2f(h3));
    uint2 hp, lp;
    hp.x = (uint32_t)h0 | ((uint32_t)h1 << 16);
    hp.y = (uint32_t)h2 | ((uint32_t)h3 << 16);
    lp.x = (uint32_t)l0 | ((uint32_t)l1 << 16);
    lp.y = (uint32_t)l2 | ((uint32_t)l3 << 16);
    *(uint2*)(hi + 4 * (size_t)i) = hp;
    *(uint2*)(lo + 4 * (size_t)i) = lp;
}

// ---------------- MFMA split-bf16 GEMM ----------------
// A staged in LDS (dbuf 2x16KB, global_load_lds); W fragments held in REGISTERS
// with one-step-ahead register double-buffer (W is 0.5MB, L2-resident, reused by
// all row-blocks -> no reason to re-stage through LDS). Barrier only drains the
// 16KB A-stage per K-step (was 32KB).

__global__ __launch_bounds__(256, 2) void gemm_mfma(
    const unsigned short* __restrict__ Ah, const unsigned short* __restrict__ Al,
    const unsigned short* __restrict__ Wh, const unsigned short* __restrict__ Wl,
    _Float16* __restrict__ out16, int M) {
    __shared__ unsigned short sAh[2][128][32], sAl[2][128][32];
    const int t = threadIdx.x;
    const int m0 = blockIdx.x * 128, n0 = blockIdx.y * 128;
    const int lane = t & 63, w = t >> 6;
    const int wr = w >> 1, wc = w & 1;
    const int fr = lane & 15, fg = lane >> 4;

    // A staging: unit u (16B) covers row u>>2, col8 (u&3)*8; thread t -> u=t, u=t+256
    const int rowA0 = t >> 2, cbA0 = (t & 3) * 8;
    const int rowA1 = rowA0 + 64, cbA1 = cbA0;
    int gra0 = m0 + rowA0; gra0 = gra0 < M ? gra0 : M - 1;
    int gra1 = m0 + rowA1; gra1 = gra1 < M ? gra1 : M - 1;

    auto stageA = [&](int b, int kc) {
        __builtin_amdgcn_global_load_lds((gas_t)(Ah + (size_t)gra0 * HC + kc + cbA0), (las_t)&sAh[b][rowA0][cbA0], 16, 0, 0);
        __builtin_amdgcn_global_load_lds((gas_t)(Ah + (size_t)gra1 * HC + kc + cbA1), (las_t)&sAh[b][rowA1][cbA1], 16, 0, 0);
        __builtin_amdgcn_global_load_lds((gas_t)(Al + (size_t)gra0 * HC + kc + cbA0), (las_t)&sAl[b][rowA0][cbA0], 16, 0, 0);
        __builtin_amdgcn_global_load_lds((gas_t)(Al + (size_t)gra1 * HC + kc + cbA1), (las_t)&sAl[b][rowA1][cbA1], 16, 0, 0);
    };

    // W fragment addresses for this wave (rows = output cols of its quadrant)
    const unsigned short* wph[4];
    const unsigned short* wpl[4];
#pragma unroll
    for (int i = 0; i < 4; i++) {
        int grw = n0 + wc * 64 + i * 16 + fr;
        wph[i] = Wh + (size_t)grw * HC + fg * 8;
        wpl[i] = Wl + (size_t)grw * HC + fg * 8;
    }

    f32x4 acc[4][4];
#pragma unroll
    for (int mi = 0; mi < 4; mi++)
#pragma unroll
        for (int ni = 0; ni < 4; ni++) acc[mi][ni] = (f32x4){0.f, 0.f, 0.f, 0.f};

    short8v bh[4], bl[4], bhn[4], bln[4];
#pragma unroll
    for (int i = 0; i < 4; i++) {
        bh[i] = *(const short8v*)(wph[i]);
        bl[i] = *(const short8v*)(wpl[i]);
    }
    stageA(0, 0);
    __syncthreads();

#pragma unroll
    for (int kt = 0; kt < 8; kt++) {
        const int kc = kt * 32;
        if (kt < 7) {
            stageA((kt + 1) & 1, kc + 32);          // prefetch next A tile (LDS)
#pragma unroll
            for (int i = 0; i < 4; i++) {           // prefetch next W frags (regs)
                bhn[i] = *(const short8v*)(wph[i] + kc + 32);
                bln[i] = *(const short8v*)(wpl[i] + kc + 32);
            }
        }
        const int b = kt & 1;
        short8v a_h[4], a_l[4];
#pragma unroll
        for (int i = 0; i < 4; i++) {
            a_h[i] = *(const short8v*)&sAh[b][wr * 64 + i * 16 + fr][fg * 8];
            a_l[i] = *(const short8v*)&sAl[b][wr * 64 + i * 16 + fr][fg * 8];
        }
#pragma unroll
        for (int mi = 0; mi < 4; mi++)
#pragma unroll
            for (int ni = 0; ni < 4; ni++) {
                acc[mi][ni] = __builtin_amdgcn_mfma_f32_16x16x32_bf16(a_h[mi], bh[ni], acc[mi][ni], 0, 0, 0);
                acc[mi][ni] = __builtin_amdgcn_mfma_f32_16x16x32_bf16(a_h[mi], bl[ni], acc[mi][ni], 0, 0, 0);
                acc[mi][ni] = __builtin_amdgcn_mfma_f32_16x16x32_bf16(a_l[mi], bh[ni], acc[mi][ni], 0, 0, 0);
            }
        if (kt < 7) {
#pragma unroll
            for (int i = 0; i < 4; i++) { bh[i] = bhn[i]; bl[i] = bln[i]; }
        }
        __syncthreads();
    }

#pragma unroll
    for (int mi = 0; mi < 4; mi++) {
#pragma unroll
        for (int r = 0; r < 4; r++) {
            int gr = m0 + wr * 64 + mi * 16 + fg * 4 + r;
            if (gr < M) {
#pragma unroll
                for (int ni = 0; ni < 4; ni++) {
                    out16[(size_t)gr * HC + n0 + wc * 64 + ni * 16 + fr] = (_Float16)acc[mi][ni][r];
                }
            }
        }
    }
}

// ---------------- per-(node,head) attention logits (wave-per-row, 8B loads) -----

__global__ void alpha_hc(const _Float16* __restrict__ h16, const float* __restrict__ a_s,
                         const float* __restrict__ a_d, float* __restrict__ asrc,
                         float* __restrict__ adst) {
    int n = blockIdx.x * 4 + (threadIdx.x >> 6);
    int lane = threadIdx.x & 63;
    uint2 raw = *(const uint2*)(h16 + (size_t)n * HC + lane * 4);
    __half2 p0 = *(__half2*)&raw.x;
    __half2 p1 = *(__half2*)&raw.y;
    float h0 = __low2float(p0), h1 = __high2float(p0);
    float h2 = __low2float(p1), h3 = __high2float(p1);
    float4 s4 = *(const float4*)(a_s + lane * 4);
    float4 d4 = *(const float4*)(a_d + lane * 4);
    float ps = h0 * s4.x + h1 * s4.y + h2 * s4.z + h3 * s4.w;
    float pd = h0 * d4.x + h1 * d4.y + h2 * d4.z + h3 * d4.w;
#pragma unroll
    for (int o = 1; o < 16; o <<= 1) {
        ps += __shfl_xor(ps, o);
        pd += __shfl_xor(pd, o);
    }
    if ((lane & 15) == 0) {
        int hh = lane >> 4;
        asrc[n * 4 + hh] = ps;
        adst[n * 4 + hh] = pd;
    }
}

// ---------------- fused segment softmax + aggregation (layers 1,2) ----------------
// 8 nodes/block; gather group i == node i, lane q = channels 8q..8q+7.
// Gather loop is 2-deep software pipelined (next row load in flight while
// accumulating current) to double outstanding memory requests per group.

#define CHUNK 384
#define NPB 8

__global__ void aggregate_hc(const _Float16* __restrict__ h16, const float* __restrict__ asrc,
                             const float* __restrict__ adst, const int* __restrict__ rp,
                             const int* __restrict__ csr, const float* __restrict__ bias,
                             float* __restrict__ y, unsigned short* __restrict__ yh,
                             unsigned short* __restrict__ yl, int flags) {
    __shared__ int   sIdx[CHUNK];
    __shared__ int   sOff[NPB + 1];
    __shared__ float sE4[CHUNK][4];
    __shared__ float sM[NPB][4], sS[NPB][4];
    __shared__ float sAd[NPB][4];
    int n0 = blockIdx.x * NPB;
    int t = threadIdx.x;
    int r0 = rp[n0];
    int tot = rp[n0 + NPB] - r0;

    if (tot <= CHUNK) {
        if (t <= NPB) sOff[t] = rp[n0 + t] - r0;
        if (t >= 32 && t < 32 + NPB * 4) {
            int i = (t - 32) >> 2, hh = t & 3;
            sAd[i][hh] = adst[(n0 + i) * 4 + hh];
        }
        for (int j = t; j < tot; j += 256) sIdx[j] = csr[r0 + j];
        __syncthreads();

        int i = t >> 5, q = t & 31, hh = q >> 3, slot = q & 7;
        int js = sOff[i], je = sOff[i + 1];

        // phase A: logits + per-(node,head) max
        float adh = sAd[i][hh];
        float pm = -1e30f;
        for (int j = js + slot; j < je; j += 8) {
            int s = sIdx[j];
            float e = asrc[s * 4 + hh] + adh;
            e = e > 0.f ? e : 0.2f * e;
            sE4[j][hh] = e;
            pm = fmaxf(pm, e);
        }
#pragma unroll
        for (int o = 1; o < 8; o <<= 1) pm = fmaxf(pm, __shfl_xor(pm, o));
        if (slot == 0) sM[i][hh] = pm;
        __syncthreads();

        // phase B: exp + per-(node,head) sum
        float mh = sM[i][hh];
        float ps = 0.f;
        for (int j = js + slot; j < je; j += 8) {
            float ex = __expf(sE4[j][hh] - mh);
            sE4[j][hh] = ex;
            ps += ex;
        }
#pragma unroll
        for (int o = 1; o < 8; o <<= 1) ps += __shfl_xor(ps, o);
        if (slot == 0) sS[i][hh] = ps;
        __syncthreads();

        // gather (2-deep pipelined): group i == node i; lane q -> ch 8q..8q+7
        float a[8];
#pragma unroll
        for (int k = 0; k < 8; k++) a[k] = 0.f;
        if (js < je) {
            uint4 raw = *(const uint4*)(h16 + (size_t)sIdx[js] * HC + 8 * q);
            for (int j = js; j < je; j++) {
                uint4 cur = raw;
                if (j + 1 < je) raw = *(const uint4*)(h16 + (size_t)sIdx[j + 1] * HC + 8 * q);
                float aw = sE4[j][hh];
                const _Float16* hv = reinterpret_cast<const _Float16*>(&cur);
#pragma unroll
                for (int k = 0; k < 8; k++) a[k] = fmaf((float)hv[k], aw, a[k]);
            }
        }
        float inv = 1.f / sS[i][hh];
        size_t base = (size_t)(n0 + i) * HC + 8 * q;
#pragma unroll
        for (int k = 0; k < 8; k++) {
            float outv = a[k] * inv + bias[8 * q + k];
            outv = outv > 0.f ? outv : expm1f(outv);
            if (flags & 1) y[base + k] = outv;
            if (flags & 2) {
                unsigned short hi = f2bf(outv);
                yh[base + k] = hi;
                yl[base + k] = f2bf(outv - bf2f(hi));
            }
        }
    } else {
        // fallback: per-node, wave w == head w (unreachable for this graph size)
        for (int i = 0; i < NPB; i++) {
            int n = n0 + i;
            int rr0 = rp[n], deg = rp[n + 1] - rr0;
            int w = t >> 6, l = t & 63;
            float ad = adst[n * 4 + w];
            int hoff = (w << 6) + l;
            const _Float16* hp = h16 + hoff;
            float m = -1e30f;
            for (int j = l; j < deg; j += 64) {
                int s = csr[rr0 + j];
                float e = asrc[s * 4 + w] + ad;
                e = e > 0.f ? e : 0.2f * e;
                m = fmaxf(m, e);
            }
#pragma unroll
            for (int o = 32; o > 0; o >>= 1) m = fmaxf(m, __shfl_xor(m, o));
            float acc = 0.f, ssum = 0.f;
            for (int j = 0; j < deg; j++) {
                int s = csr[rr0 + j];
                float e = asrc[s * 4 + w] + ad;
                e = e > 0.f ? e : 0.2f * e;
                float aa = __expf(e - m);
                ssum += aa;
                acc = fmaf(aa, (float)hp[(size_t)s * HC], acc);
            }
            float outv = acc / ssum + bias[hoff];
            outv = outv > 0.f ? outv : expm1f(outv);
            size_t off = (size_t)n * HC + hoff;
            if (flags & 1) y[off] = outv;
            if (flags & 2) {
                unsigned short hi = f2bf(outv);
                yh[off] = hi;
                yl[off] = f2bf(outv - bf2f(hi));
            }
        }
    }
}

// ---------------- layer 3 ----------------

__global__ void gemm_small(const float* __restrict__ Y, const float* __restrict__ W3,
                           float* __restrict__ h3) {
    int idx = blockIdx.x * 256 + threadIdx.x;
    if (idx >= NNODES * 12) return;
    int n = idx / 12, o = idx - n * 12;
    const float4* xr = (const float4*)(Y + (size_t)n * HC);
    const float4* wr = (const float4*)(W3 + o * HC);
    float acc = 0.f;
#pragma unroll 8
    for (int k = 0; k < 64; k++) {
        float4 a = xr[k], b = wr[k];
        acc += a.x * b.x + a.y * b.y + a.z * b.z + a.w * b.w;
    }
    h3[idx] = acc;
}

__global__ void alpha3(const float* __restrict__ h3, const float* __restrict__ a_s,
                       const float* __restrict__ a_d, float* __restrict__ asrc,
                       float* __restrict__ adst) {
    int n = blockIdx.x * 256 + threadIdx.x;
    if (n >= NNODES) return;
    const float* hr = h3 + (size_t)n * 12;
    float s[4], d[4];
#pragma unroll
    for (int hh = 0; hh < 4; hh++) {
        s[hh] = hr[hh * 3] * a_s[hh * 3] + hr[hh * 3 + 1] * a_s[hh * 3 + 1] + hr[hh * 3 + 2] * a_s[hh * 3 + 2];
        d[hh] = hr[hh * 3] * a_d[hh * 3] + hr[hh * 3 + 1] * a_d[hh * 3 + 1] + hr[hh * 3 + 2] * a_d[hh * 3 + 2];
    }
    *(float4*)(asrc + n * 4) = make_float4(s[0], s[1], s[2], s[3]);
    *(float4*)(adst + n * 4) = make_float4(d[0], d[1], d[2], d[3]);
}

__global__ void aggregate3(const float* __restrict__ h3, const float* __restrict__ asrc,
                           const float* __restrict__ adst, const int* __restrict__ rp,
                           const int* __restrict__ csr, const float* __restrict__ b3,
                           float* __restrict__ out) {
    int n = blockIdx.x * 4 + (threadIdx.x >> 6);
    int l = threadIdx.x & 63;
    if (n >= NNODES) return;
    int r0 = rp[n], deg = rp[n + 1] - r0;
    float4 ad = *(const float4*)(adst + n * 4);

    float m0 = -1e30f, m1 = -1e30f, m2 = -1e30f, m3 = -1e30f;
    for (int j = l; j < deg; j += 64) {
        int s = csr[r0 + j];
        float4 a4 = *(const float4*)(asrc + s * 4);
        float e0 = a4.x + ad.x, e1 = a4.y + ad.y, e2 = a4.z + ad.z, e3 = a4.w + ad.w;
        e0 = e0 > 0.f ? e0 : 0.2f * e0;
        e1 = e1 > 0.f ? e1 : 0.2f * e1;
        e2 = e2 > 0.f ? e2 : 0.2f * e2;
        e3 = e3 > 0.f ? e3 : 0.2f * e3;
        m0 = fmaxf(m0, e0); m1 = fmaxf(m1, e1); m2 = fmaxf(m2, e2); m3 = fmaxf(m3, e3);
    }
    for (int o = 32; o > 0; o >>= 1) {
        m0 = fmaxf(m0, __shfl_xor(m0, o));
        m1 = fmaxf(m1, __shfl_xor(m1, o));
        m2 = fmaxf(m2, __shfl_xor(m2, o));
        m3 = fmaxf(m3, __shfl_xor(m3, o));
    }

    float acc[12];
#pragma unroll
    for (int k = 0; k < 12; k++) acc[k] = 0.f;
    float s0 = 0.f, s1 = 0.f, s2 = 0.f, s3 = 0.f;
    for (int j = l; j < deg; j += 64) {
        int s = csr[r0 + j];
        float4 a4 = *(const float4*)(asrc + s * 4);
        float e0 = a4.x + ad.x, e1 = a4.y + ad.y, e2 = a4.z + ad.z, e3 = a4.w + ad.w;
        e0 = e0 > 0.f ? e0 : 0.2f * e0;
        e1 = e1 > 0.f ? e1 : 0.2f * e1;
        e2 = e2 > 0.f ? e2 : 0.2f * e2;
        e3 = e3 > 0.f ? e3 : 0.2f * e3;
        float w0 = __expf(e0 - m0), w1 = __expf(e1 - m1), w2 = __expf(e2 - m2), w3 = __expf(e3 - m3);
        s0 += w0; s1 += w1; s2 += w2; s3 += w3;
        const float* hr = h3 + (size_t)s * 12;
#pragma unroll
        for (int c = 0; c < 3; c++) {
            acc[c]     += w0 * hr[c];
            acc[3 + c] += w1 * hr[3 + c];
            acc[6 + c] += w2 * hr[6 + c];
            acc[9 + c] += w3 * hr[9 + c];
        }
    }
    for (int o = 32; o > 0; o >>= 1) {
#pragma unroll
        for (int k = 0; k < 12; k++) acc[k] += __shfl_xor(acc[k], o);
        s0 += __shfl_xor(s0, o);
        s1 += __shfl_xor(s1, o);
        s2 += __shfl_xor(s2, o);
        s3 += __shfl_xor(s3, o);
    }
    if (l < 3) {
        float v = 0.25f * (acc[l] / s0 + acc[3 + l] / s1 + acc[6 + l] / s2 + acc[9 + l] / s3) + b3[l];
        v = v > 0.f ? v : expm1f(v);
        out[(size_t)n * 3 + l] = v;
    }
}

// ---------------- launch ----------------

extern "C" void kernel_launch(void* const* d_in, const int* in_sizes, int n_in,
                              void* d_out, int out_size, void* d_ws, size_t ws_size,
                              hipStream_t stream) {
    (void)in_sizes; (void)n_in; (void)out_size; (void)ws_size;
    const float* x   = (const float*)d_in[0];
    const int*   ei  = (const int*)d_in[1];
    const float* W1  = (const float*)d_in[2];
    const float* as1 = (const float*)d_in[3];
    const float* ad1 = (const float*)d_in[4];
    const float* b1  = (const float*)d_in[5];
    const float* W2  = (const float*)d_in[6];
    const float* as2 = (const float*)d_in[7];
    const float* ad2 = (const float*)d_in[8];
    const float* b2  = (const float*)d_in[9];
    const float* W3  = (const float*)d_in[10];
    const float* as3 = (const float*)d_in[11];
    const float* ad3 = (const float*)d_in[12];
    const float* b3  = (const float*)d_in[13];
    float* out = (float*)d_out;

    uint8_t* p = (uint8_t*)d_ws;
    auto alloc = [&](size_t bytes) -> void* {
        void* r = (void*)p;
        p += (bytes + 255) & ~(size_t)255;
        return r;
    };
    float* bufY = (float*)alloc((size_t)NNODES * HC * 4);
    float* h3   = (float*)alloc((size_t)NNODES * 12 * 4);
    float* asrc = (float*)alloc((size_t)NNODES * 4 * 4);
    float* adst = (float*)alloc((size_t)NNODES * 4 * 4);
    int* deg    = (int*)alloc((size_t)NNODES * 4);
    int* rp     = (int*)alloc((size_t)(NNODES + 1) * 4);
    int* cnt    = (int*)alloc((size_t)NNODES * 4);
    int* csr    = (int*)alloc((size_t)E2 * 4);
    int* bsums  = (int*)alloc(256 * 4);
    unsigned short* xh  = (unsigned short*)alloc((size_t)NNODES * HC * 2);
    unsigned short* xl  = (unsigned short*)alloc((size_t)NNODES * HC * 2);
    unsigned short* w1h = (unsigned short*)alloc((size_t)HC * HC * 2);
    unsigned short* w1l = (unsigned short*)alloc((size_t)HC * HC * 2);
    unsigned short* w2h = (unsigned short*)alloc((size_t)HC * HC * 2);
    unsigned short* w2l = (unsigned short*)alloc((size_t)HC * HC * 2);
    _Float16* h16 = (_Float16*)alloc((size_t)NNODES * HC * 2);

    const int NB_N = (NNODES + 255) / 256;
    const int NB_E = (E2 + 255) / 256;
    const int N4_A = NNODES * HC / 4;
    const int N4_W = HC * HC / 4;

    // CSR build
    zero_int<<<NB_N, 256, 0, stream>>>(deg, NNODES);
    count_deg<<<NB_E, 256, 0, stream>>>(ei, deg);
    scan1<<<NB_N, 256, 0, stream>>>(deg, rp, bsums);
    scan2<<<1, 256, 0, stream>>>(bsums, NB_N);
    scan3<<<NB_N, 256, 0, stream>>>(rp, bsums, cnt);
    fill_csr<<<NB_E, 256, 0, stream>>>(ei, cnt, csr);

    dim3 ggrid((NNODES + 127) / 128, 2);

    // Layer 1
    split_bf16<<<(N4_W + 255) / 256, 256, 0, stream>>>(W1, w1h, w1l, N4_W);
    split_bf16<<<(N4_A + 255) / 256, 256, 0, stream>>>(x, xh, xl, N4_A);
    gemm_mfma<<<ggrid, 256, 0, stream>>>(xh, xl, w1h, w1l, h16, NNODES);
    alpha_hc<<<NNODES / 4, 256, 0, stream>>>(h16, as1, ad1, asrc, adst);
    aggregate_hc<<<NNODES / NPB, 256, 0, stream>>>(h16, asrc, adst, rp, csr, b1, bufY, xh, xl, 2);

    // Layer 2
    split_bf16<<<(N4_W + 255) / 256, 256, 0, stream>>>(W2, w2h, w2l, N4_W);
    gemm_mfma<<<ggrid, 256, 0, stream>>>(xh, xl, w2h, w2l, h16, NNODES);
    alpha_hc<<<NNODES / 4, 256, 0, stream>>>(h16, as2, ad2, asrc, adst);
    aggregate_hc<<<NNODES / NPB, 256, 0, stream>>>(h16, asrc, adst, rp, csr, b2, bufY, xh, xl, 1);

    // Layer 3
    gemm_small<<<(NNODES * 12 + 255) / 256, 256, 0, stream>>>(bufY, W3, h3);
    alpha3<<<NB_N, 256, 0, stream>>>(h3, as3, ad3, asrc, adst);
    aggregate3<<<(NNODES + 3) / 4, 256, 0, stream>>>(h3, asrc, adst, rp, csr, b3, out);
}